// Round 5
// baseline (282.869 us; speedup 1.0000x reference)
//
#include <hip/hip_runtime.h>
#include <math.h>

// ---------------------------------------------------------------------------
// PredictiveModule fused persistent kernel, R5.
// R4 diagnosis: hbm_gbps=1117 (14% peak), VALUBusy=3.2%, occupancy 43% =>
// waves stalled on vmcnt with <1 outstanding load each (CP=1 inner loops).
// R5: all three matvec phases rewritten with explicit register double-buffer:
// 4 independent float4 loads per iteration (named regs, fully unrolled, no
// runtime-indexed arrays), FMA consumes previous group while next is in
// flight. Per-CU in-flight = 16 waves x 4KB = 64KB >> ~12KB needed for the
// 10 B/cy/CU HBM fair share.
//
// Phases (256 blocks x 1024 threads, 1 block/CU, device barriers between):
//   P1: p1[256][4096]  partials of ct @ W1      (64 rows/block)
//   P2: reduce->x2, p2[256][4096] partials @ W2 (16 rows/block)
//   P3: reduce->x3, p3[128][16384] partials @ W3 (32 rows/pair, half cols)
//   P4: reduce p3 + gate/clip/sample + logprob partials
//   P5: block 0 radix-select top-k (stable ties) + final writes
//
// Numerics: f64 accumulation (HBM-bound, f64 free); f32 rounding mimicked
// only at sample = f32(am) + 0.05f*noise. absmax must stay 0.
// ---------------------------------------------------------------------------

constexpr int D   = 16384;
constexpr int H   = 4096;
constexpr int NB  = 256;
constexpr int T   = 1024;
constexpr int KC1 = D / NB;     // 64
constexpr int KC2 = H / NB;     // 16
constexpr int NP3 = NB / 2;     // 128
constexpr int KC3 = H / NP3;    // 32

__device__ __forceinline__ double wredsum(double v) {
    #pragma unroll
    for (int o = 32; o > 0; o >>= 1) v += __shfl_down(v, o, 64);
    return v;
}

__device__ __forceinline__ void gbar(int* bar, int phase) {
    __syncthreads();
    if (threadIdx.x == 0) {
        __threadfence();
        if (atomicAdd(&bar[phase], 1) == NB - 1)
            atomicAdd(&bar[15], 1);  // generation: monotonic 0 -> 4
        while (__hip_atomic_load(&bar[15], __ATOMIC_ACQUIRE,
                                 __HIP_MEMORY_SCOPE_AGENT) < phase + 1)
            __builtin_amdgcn_s_sleep(2);
        __threadfence();
    }
    __syncthreads();
}

__global__ __launch_bounds__(T, 4) void k_fused(
    const float* __restrict__ ct,  const float* __restrict__ W1,
    const float* __restrict__ b1,  const float* __restrict__ W2,
    const float* __restrict__ b2,  const float* __restrict__ W3,
    const float* __restrict__ b3,  const float* __restrict__ qm,
    const float* __restrict__ noise, const int* __restrict__ kptr,
    int* bar, double* p1, double* p2, double* p3,
    float* samp, double* lpp, float* out)
{
    __shared__ union {
        struct { double xs[KC1]; double xred[T]; } mv;
        struct {
            int whist[16][257];
            int hist[256]; int sfx[256];
            int wsum[16]; int wcnt[4];
            unsigned int s_prefix; int s_kk;
        } tk;
    } sm;

    const int b = blockIdx.x, t = threadIdx.x;
    const int lane = t & 63, wid = t >> 6;

    // ---------------- P1: rows [b*64, +64) of W1 (K=D, N=H) ----------------
    {
        if (t < KC1) sm.mv.xs[t] = (double)ct[b * KC1 + t];
        __syncthreads();
        const float* Wp = W1 + (size_t)(b * KC1) * H + (size_t)t * 4;
        double a0 = 0, a1 = 0, a2 = 0, a3 = 0;
        float4 c0, c1, c2, c3, n0, n1, n2, n3;
        #define LDW(dst, row) dst = *reinterpret_cast<const float4*>(Wp + (size_t)(row) * H)
        #define FMA4(v, xr) { const double x_ = (xr); \
            a0 += x_ * (double)v.x; a1 += x_ * (double)v.y; \
            a2 += x_ * (double)v.z; a3 += x_ * (double)v.w; }
        LDW(c0, 0); LDW(c1, 1); LDW(c2, 2); LDW(c3, 3);
        #pragma unroll
        for (int g = 0; g < KC1 / 4; g += 2) {
            const int rn = (g + 1) * 4;
            LDW(n0, rn + 0); LDW(n1, rn + 1); LDW(n2, rn + 2); LDW(n3, rn + 3);
            FMA4(c0, sm.mv.xs[g * 4 + 0]); FMA4(c1, sm.mv.xs[g * 4 + 1]);
            FMA4(c2, sm.mv.xs[g * 4 + 2]); FMA4(c3, sm.mv.xs[g * 4 + 3]);
            if (g + 2 < KC1 / 4) {
                const int rc = (g + 2) * 4;
                LDW(c0, rc + 0); LDW(c1, rc + 1); LDW(c2, rc + 2); LDW(c3, rc + 3);
            }
            FMA4(n0, sm.mv.xs[rn + 0]); FMA4(n1, sm.mv.xs[rn + 1]);
            FMA4(n2, sm.mv.xs[rn + 2]); FMA4(n3, sm.mv.xs[rn + 3]);
        }
        #undef LDW
        double* yp = p1 + (size_t)b * H + t * 4;
        *reinterpret_cast<double2*>(yp + 0) = make_double2(a0, a1);
        *reinterpret_cast<double2*>(yp + 2) = make_double2(a2, a3);
    }
    gbar(bar, 0);

    // ---------------- P2: rows [b*16, +16) of W2 (K=H, N=H) ----------------
    {
        const int j0 = b * KC2;
        const int jl = t & (KC2 - 1), sl = t / KC2;     // 64 slices
        double s = 0;
        #pragma unroll
        for (int g = sl; g < NB; g += T / KC2)          // 4 iters
            s += p1[(size_t)g * H + j0 + jl];
        sm.mv.xred[t] = s;
        __syncthreads();
        if (t < KC2) {
            double tot = (double)b1[j0 + t];
            #pragma unroll
            for (int s2 = 0; s2 < T / KC2; ++s2) tot += sm.mv.xred[s2 * KC2 + t];
            sm.mv.xs[t] = tot > 0.0 ? tot : 0.0;        // relu
        }
        __syncthreads();
        const float* Wp = W2 + (size_t)j0 * H + (size_t)t * 4;
        double a0 = 0, a1 = 0, a2 = 0, a3 = 0;
        float4 c0, c1, c2, c3, n0, n1, n2, n3;
        #define LDW(dst, row) dst = *reinterpret_cast<const float4*>(Wp + (size_t)(row) * H)
        LDW(c0, 0); LDW(c1, 1); LDW(c2, 2); LDW(c3, 3);
        #pragma unroll
        for (int g = 0; g < KC2 / 4; g += 2) {
            const int rn = (g + 1) * 4;
            LDW(n0, rn + 0); LDW(n1, rn + 1); LDW(n2, rn + 2); LDW(n3, rn + 3);
            FMA4(c0, sm.mv.xs[g * 4 + 0]); FMA4(c1, sm.mv.xs[g * 4 + 1]);
            FMA4(c2, sm.mv.xs[g * 4 + 2]); FMA4(c3, sm.mv.xs[g * 4 + 3]);
            if (g + 2 < KC2 / 4) {
                const int rc = (g + 2) * 4;
                LDW(c0, rc + 0); LDW(c1, rc + 1); LDW(c2, rc + 2); LDW(c3, rc + 3);
            }
            FMA4(n0, sm.mv.xs[rn + 0]); FMA4(n1, sm.mv.xs[rn + 1]);
            FMA4(n2, sm.mv.xs[rn + 2]); FMA4(n3, sm.mv.xs[rn + 3]);
        }
        #undef LDW
        #undef FMA4
        double* yp = p2 + (size_t)b * H + t * 4;
        *reinterpret_cast<double2*>(yp + 0) = make_double2(a0, a1);
        *reinterpret_cast<double2*>(yp + 2) = make_double2(a2, a3);
    }
    gbar(bar, 1);

    // ------- P3: block pair p=b>>1: rows [p*32,+32) of W3 (K=H, N=D) -------
    {
        const int p = b >> 1, h = b & 1;
        const int j0 = p * KC3;
        const int jl = t & (KC3 - 1), sl = t / KC3;     // 32 slices
        double s = 0;
        #pragma unroll
        for (int g = sl; g < NB; g += T / KC3)          // 8 iters
            s += p2[(size_t)g * H + j0 + jl];
        sm.mv.xred[t] = s;
        __syncthreads();
        if (t < KC3) {
            double tot = (double)b2[j0 + t];
            #pragma unroll
            for (int s2 = 0; s2 < T / KC3; ++s2) tot += sm.mv.xred[s2 * KC3 + t];
            sm.mv.xs[t] = tot > 0.0 ? tot : 0.0;        // relu
        }
        __syncthreads();
        // two quads per thread: q0 = h*8192 + t*4, q1 = q0 + 4096 (floats)
        const float* Wp = W3 + (size_t)j0 * D + (size_t)(h * (D / 2)) + (size_t)t * 4;
        double a0 = 0, a1 = 0, a2 = 0, a3 = 0, a4 = 0, a5 = 0, a6 = 0, a7 = 0;
        float4 c0, c1, c2, c3, n0, n1, n2, n3;  // (row0,q0)(row0,q1)(row1,q0)(row1,q1)
        #define LDW3(dst, row, q) dst = *reinterpret_cast<const float4*>( \
            Wp + (size_t)(row) * D + (q) * (D / 4))
        #define FMA8(u, v, xr) { const double x_ = (xr); \
            a0 += x_ * (double)u.x; a1 += x_ * (double)u.y; \
            a2 += x_ * (double)u.z; a3 += x_ * (double)u.w; \
            a4 += x_ * (double)v.x; a5 += x_ * (double)v.y; \
            a6 += x_ * (double)v.z; a7 += x_ * (double)v.w; }
        LDW3(c0, 0, 0); LDW3(c1, 0, 1); LDW3(c2, 1, 0); LDW3(c3, 1, 1);
        #pragma unroll
        for (int g = 0; g < KC3 / 2; g += 2) {
            const int rn = (g + 1) * 2;
            LDW3(n0, rn, 0); LDW3(n1, rn, 1); LDW3(n2, rn + 1, 0); LDW3(n3, rn + 1, 1);
            FMA8(c0, c1, sm.mv.xs[g * 2 + 0]);
            FMA8(c2, c3, sm.mv.xs[g * 2 + 1]);
            if (g + 2 < KC3 / 2) {
                const int rc = (g + 2) * 2;
                LDW3(c0, rc, 0); LDW3(c1, rc, 1); LDW3(c2, rc + 1, 0); LDW3(c3, rc + 1, 1);
            }
            FMA8(n0, n1, sm.mv.xs[rn + 0]);
            FMA8(n2, n3, sm.mv.xs[rn + 1]);
        }
        #undef LDW3
        #undef FMA8
        double* y0 = p3 + (size_t)p * D + (size_t)(h * (D / 2)) + t * 4;
        double* y1 = y0 + D / 4;
        *reinterpret_cast<double2*>(y0 + 0) = make_double2(a0, a1);
        *reinterpret_cast<double2*>(y0 + 2) = make_double2(a2, a3);
        *reinterpret_cast<double2*>(y1 + 0) = make_double2(a4, a5);
        *reinterpret_cast<double2*>(y1 + 2) = make_double2(a6, a7);
    }
    gbar(bar, 2);

    // ------------- P4: reduce p3, elementwise, logprob partials -------------
    {
        const int c0 = b * (D / NB);                    // 64 cols per block
        const int cl = t & 63, gs = t >> 6;             // 16 g-slices
        double s = 0;
        #pragma unroll
        for (int g = gs; g < NP3; g += 16)              // 8 iters
            s += p3[(size_t)g * D + c0 + cl];
        sm.mv.xred[gs * 64 + cl] = s;
        __syncthreads();
        if (t < 64) {
            const int c = c0 + t;
            double vm = (double)b3[c];
            #pragma unroll
            for (int s2 = 0; s2 < 16; ++s2) vm += sm.mv.xred[s2 * 64 + t];
            vm = vm > 100.0 ? 100.0 : (vm < -100.0 ? -100.0 : vm);
            const double z = (double)qm[c] * (double)ct[c];
            const double g = 1.0 / (1.0 + exp(-z));
            double am = g * vm;                          // influence == 1.0
            am = am > 1000.0 ? 1000.0 : (am < -1000.0 ? -1000.0 : am);
            const float amf = (float)am;
            const float sp = amf + 0.05f * noise[c];
            samp[c] = sp;
            const float df = (sp - amf) / 0.05f;
            double term = (double)df * (double)df;
            term = wredsum(term);                        // t<64 == wave 0
            if (t == 0) lpp[b] = term;
        }
    }
    gbar(bar, 3);

    // ---------------- P5: block 0 only — top-k + final write ----------------
    if (b != 0) return;

    const int k = *kptr;
    unsigned int prefix = 0;
    int kk = k;
    for (int pass = 0; pass < 4; ++pass) {
        const int shift = 24 - 8 * pass;
        const unsigned int dm = pass ? (0xffffffffu << (32 - 8 * pass)) : 0u;
        for (int i = t; i < 16 * 257; i += T) (&sm.tk.whist[0][0])[i] = 0;
        __syncthreads();
        for (int i = t; i < D; i += T) {
            const unsigned int v = __float_as_uint(samp[i]) & 0x7fffffffu;
            if ((v & dm) == prefix)
                atomicAdd(&sm.tk.whist[wid][(v >> shift) & 0xff], 1);
        }
        __syncthreads();
        if (t < 256) {
            int s = 0;
            #pragma unroll
            for (int w = 0; w < 16; ++w) s += sm.tk.whist[w][t];
            sm.tk.hist[t] = s;
            sm.tk.sfx[t] = s;
        }
        __syncthreads();
        #pragma unroll
        for (int off = 1; off < 256; off <<= 1) {
            int add = 0;
            if (t < 256 && t + off < 256) add = sm.tk.sfx[t + off];
            __syncthreads();
            if (t < 256) sm.tk.sfx[t] += add;
            __syncthreads();
        }
        const bool cond = (t < 256) && (sm.tk.sfx[t] >= kk);
        const unsigned long long m = __ballot(cond);
        if (lane == 0 && wid < 4) sm.tk.wcnt[wid] = __popcll(m);
        __syncthreads();
        if (t == 0) {
            const int bs = sm.tk.wcnt[0] + sm.tk.wcnt[1] + sm.tk.wcnt[2] + sm.tk.wcnt[3] - 1;
            sm.tk.s_kk = kk - (sm.tk.sfx[bs] - sm.tk.hist[bs]);
            sm.tk.s_prefix = prefix | ((unsigned int)bs << shift);
        }
        __syncthreads();
        prefix = sm.tk.s_prefix;
        kk = sm.tk.s_kk;
        __syncthreads();
    }
    const unsigned int vstar = prefix;
    const int need = kk;   // ties (lowest index) to keep

    // stable tie-rank: contiguous per-thread chunks preserve index order
    constexpr int PER = D / T;  // 16
    const int base = t * PER;
    float vals[PER];
    unsigned int keys[PER];
    int cnt = 0;
    #pragma unroll
    for (int j = 0; j < PER; ++j) {
        const float f = samp[base + j];
        vals[j] = f;
        keys[j] = __float_as_uint(f) & 0x7fffffffu;
        cnt += (keys[j] == vstar) ? 1 : 0;
    }
    int inc = cnt;                                       // wave inclusive scan
    #pragma unroll
    for (int o = 1; o < 64; o <<= 1) {
        const int n = __shfl_up(inc, o, 64);
        if (lane >= o) inc += n;
    }
    if (lane == 63) sm.tk.wsum[wid] = inc;
    __syncthreads();
    int woff = 0;
    for (int w = 0; w < wid; ++w) woff += sm.tk.wsum[w];
    int offset = woff + inc - cnt;                       // exclusive tie-rank
    #pragma unroll
    for (int j = 0; j < PER; ++j) {
        float o2 = 0.0f;
        if (keys[j] > vstar) {
            o2 = vals[j];
        } else if (keys[j] == vstar) {
            if (offset < need) o2 = vals[j];
            offset++;
        }
        out[base + j] = o2;
    }

    if (wid == 0) {                                      // logprob
        double s = 0;
        for (int g = lane; g < NB; g += 64) s += lpp[g];
        s = wredsum(s);
        if (lane == 0) {
            const double c = -log(0.05) - 0.5 * log(2.0 * 3.14159265358979323846);
            out[D] = (float)(-0.5 * s + (double)D * c);
        }
    }
}

extern "C" void kernel_launch(void* const* d_in, const int* in_sizes, int n_in,
                              void* d_out, int out_size, void* d_ws, size_t ws_size,
                              hipStream_t stream) {
    const float* ct    = (const float*)d_in[0];
    const float* W1    = (const float*)d_in[1];
    const float* b1    = (const float*)d_in[2];
    const float* W2    = (const float*)d_in[3];
    const float* b2    = (const float*)d_in[4];
    const float* W3    = (const float*)d_in[5];
    const float* b3    = (const float*)d_in[6];
    const float* qm    = (const float*)d_in[7];
    const float* noise = (const float*)d_in[8];
    const int*   kp    = (const int*)d_in[9];

    // ws: bar(256B) | p1[256][4096] | p2[256][4096] | p3[128][16384] | samp | lpp
    int*    bar  = (int*)d_ws;
    double* p1   = (double*)((char*)d_ws + 256);
    double* p2   = p1 + (size_t)NB * H;
    double* p3   = p2 + (size_t)NB * H;
    float*  samp = (float*)(p3 + (size_t)NP3 * D);
    double* lpp  = (double*)(samp + D);

    hipMemsetAsync(d_ws, 0, 256, stream);   // barrier state: deterministic
    k_fused<<<dim3(NB), dim3(T), 0, stream>>>(
        ct, W1, b1, W2, b2, W3, b3, qm, noise, kp,
        bar, p1, p2, p3, samp, lpp, (float*)d_out);
}

// Round 6
// 174.672 us; speedup vs baseline: 1.6194x; 1.6194x over previous
//
#include <hip/hip_runtime.h>
#include <math.h>

// ---------------------------------------------------------------------------
// PredictiveModule, R6: separate kernels + global_load_lds pipelined matvec.
//
// R5 diagnosis: VGPR=44 unchanged -> compiler re-serialized the explicit
// register double-buffer (1 load in flight/wave, 1.1 TB/s). Fix: async
// global->LDS staging (__builtin_amdgcn_global_load_lds) with counted
// s_waitcnt vmcnt(8): in-flight depth = LDS buffer depth (structural).
// Wave-private double buffer => no __syncthreads in the K-loop => no
// compiler-inserted vmcnt(0) drain.
//
// Pipeline per wave (owns 256 cols of the block's 1024):
//   stage tile0 (8 rows x 1KB);
//   for t: stage tile t+1 -> other buf; vmcnt(8); ds_read_b128 + f64 FMA.
//
// Dispatches: mv1 -> red1 -> mv2 -> red2 -> mv3 -> finalize -> topk.
// Numerics: f64 accumulation (matvec HBM-bound; f64 free). f32 rounding only
// at sample = f32(am) + 0.05f*noise. Top-k ties: stable by index.
// ---------------------------------------------------------------------------

constexpr int D = 16384;
constexpr int H = 4096;

__device__ __forceinline__ void stage16(const float* g, const float* l) {
    __builtin_amdgcn_global_load_lds(
        (const __attribute__((address_space(1))) unsigned int*)g,
        (__attribute__((address_space(3))) unsigned int*)l,
        16, 0, 0);
}

__device__ __forceinline__ double wredsum(double v) {
    #pragma unroll
    for (int o = 32; o > 0; o >>= 1) v += __shfl_down(v, o, 64);
    return v;
}

// Split-K matvec: grid (N/1024, K/KC). Block: 256 thr, 4 waves; wave w owns
// cols [bx*1024 + w*256, +256). Writes f64 partials ypart[by][N].
template<int KC>
__global__ __launch_bounds__(256) void k_mv(
    const float* __restrict__ W, int N,
    const float* __restrict__ xf,      // L1: ct (f32); else null
    const double* __restrict__ xd,     // L2/L3: reduced post-relu x (f64)
    double* __restrict__ ypart)
{
    constexpr int TILES = KC / 8;
    __shared__ float wbuf[4][2][8][256];   // 64 KB: wave-private dbuf
    __shared__ double xs[KC];

    const int t = threadIdx.x, lane = t & 63, w = t >> 6;
    const int k0 = blockIdx.y * KC;
    if (t < KC) xs[t] = xf ? (double)xf[k0 + t] : xd[k0 + t];
    __syncthreads();   // xs visible; nothing critical in flight yet

    const int cbase = blockIdx.x * 1024 + w * 256;
    const float* Wg = W + (size_t)k0 * N + cbase + lane * 4;
    float* b0 = &wbuf[w][0][0][0];
    float* b1 = &wbuf[w][1][0][0];

    #pragma unroll
    for (int r = 0; r < 8; ++r)                 // stage tile 0
        stage16(Wg + (size_t)r * N, b0 + r * 256);

    double a0 = 0, a1 = 0, a2 = 0, a3 = 0;
    for (int tt = 0; tt < TILES; ++tt) {
        if (tt + 1 < TILES) {
            const float* Wn = Wg + (size_t)(tt + 1) * 8 * N;
            #pragma unroll
            for (int r = 0; r < 8; ++r)         // stage tile t+1
                stage16(Wn + (size_t)r * N, b1 + r * 256);
            asm volatile("s_waitcnt vmcnt(8)" ::: "memory");  // tile t landed
        } else {
            asm volatile("s_waitcnt vmcnt(0)" ::: "memory");
        }
        #pragma unroll
        for (int r = 0; r < 8; ++r) {           // consume tile t
            const float4 wv = *reinterpret_cast<const float4*>(b0 + r * 256 + lane * 4);
            const double x = xs[tt * 8 + r];
            a0 += x * (double)wv.x; a1 += x * (double)wv.y;
            a2 += x * (double)wv.z; a3 += x * (double)wv.w;
        }
        float* tmp = b0; b0 = b1; b1 = tmp;
    }

    double* yp = ypart + (size_t)blockIdx.y * N + cbase + lane * 4;
    *reinterpret_cast<double2*>(yp + 0) = make_double2(a0, a1);
    *reinterpret_cast<double2*>(yp + 2) = make_double2(a2, a3);
}

// x[j] = relu(bias[j] + sum_g part[g][j]);  grid N/256.
__global__ __launch_bounds__(256) void k_reduce_x(
    const double* __restrict__ part, int G, int N,
    const float* __restrict__ bias, double* __restrict__ xout)
{
    const int j = blockIdx.x * 256 + threadIdx.x;
    double s0 = 0, s1 = 0;                      // 2-way ILP on the add chain
    #pragma unroll 4
    for (int g = 0; g + 1 < G; g += 2) {
        s0 += part[(size_t)g * N + j];
        s1 += part[(size_t)(g + 1) * N + j];
    }
    double s = (double)bias[j] + s0 + s1;
    xout[j] = s > 0.0 ? s : 0.0;
}

// Reduce p3 (G groups) + gate/clip/sample + per-block logprob partial.
__global__ __launch_bounds__(256) void k_finalize(
    const double* __restrict__ p3, int G,
    const float* __restrict__ b3,
    const float* __restrict__ qm,
    const float* __restrict__ ct,
    const float* __restrict__ noise,
    float* __restrict__ samp,
    double* __restrict__ lpp)
{
    const int i = blockIdx.x * 256 + threadIdx.x;
    double s0 = 0, s1 = 0;
    #pragma unroll 4
    for (int g = 0; g + 1 < G; g += 2) {
        s0 += p3[(size_t)g * D + i];
        s1 += p3[(size_t)(g + 1) * D + i];
    }
    double vm = (double)b3[i] + s0 + s1;
    vm = vm > 100.0 ? 100.0 : (vm < -100.0 ? -100.0 : vm);
    const double z = (double)qm[i] * (double)ct[i];
    const double g = 1.0 / (1.0 + exp(-z));
    double am = g * vm;                          // influence == 1.0
    am = am > 1000.0 ? 1000.0 : (am < -1000.0 ? -1000.0 : am);
    const float amf = (float)am;
    const float sp = amf + 0.05f * noise[i];
    samp[i] = sp;
    const float df = (sp - amf) / 0.05f;
    double term = (double)df * (double)df;
    term = wredsum(term);
    __shared__ double red[4];
    const int lane = threadIdx.x & 63, wid = threadIdx.x >> 6;
    if (lane == 0) red[wid] = term;
    __syncthreads();
    if (threadIdx.x == 0) lpp[blockIdx.x] = red[0] + red[1] + red[2] + red[3];
}

// Single-block radix-select top-k (stable ties by index) + final writes.
#define TPK 1024
__global__ __launch_bounds__(TPK) void k_topk(
    const float* __restrict__ samp,
    const int* __restrict__ kptr,
    const double* __restrict__ lpp, int GLP,
    float* __restrict__ out)
{
    __shared__ unsigned int u[16384];
    __shared__ int whist[16][257];
    __shared__ int hist[256];
    __shared__ int sfx[256];
    __shared__ int wsum[16];
    __shared__ int wcnt[4];
    __shared__ unsigned int s_prefix;
    __shared__ int s_kk;

    const int t = threadIdx.x;
    const int lane = t & 63, wid = t >> 6;

    for (int i = t; i < D; i += TPK)
        u[i] = __float_as_uint(samp[i]) & 0x7fffffffu;
    __syncthreads();

    const int k = *kptr;
    unsigned int prefix = 0;
    int kk = k;
    for (int pass = 0; pass < 4; ++pass) {
        const int shift = 24 - 8 * pass;
        const unsigned int dm = pass ? (0xffffffffu << (32 - 8 * pass)) : 0u;
        for (int i = t; i < 16 * 257; i += TPK) (&whist[0][0])[i] = 0;
        __syncthreads();
        for (int i = t; i < D; i += TPK) {
            const unsigned int v = u[i];
            if ((v & dm) == prefix)
                atomicAdd(&whist[wid][(v >> shift) & 0xff], 1);
        }
        __syncthreads();
        if (t < 256) {
            int s = 0;
            #pragma unroll
            for (int w = 0; w < 16; ++w) s += whist[w][t];
            hist[t] = s;
            sfx[t] = s;
        }
        __syncthreads();
        #pragma unroll
        for (int off = 1; off < 256; off <<= 1) {
            int add = 0;
            if (t < 256 && t + off < 256) add = sfx[t + off];
            __syncthreads();
            if (t < 256) sfx[t] += add;
            __syncthreads();
        }
        const bool cond = (t < 256) && (sfx[t] >= kk);
        const unsigned long long m = __ballot(cond);
        if (lane == 0 && wid < 4) wcnt[wid] = __popcll(m);
        __syncthreads();
        if (t == 0) {
            const int bs = wcnt[0] + wcnt[1] + wcnt[2] + wcnt[3] - 1;
            s_kk = kk - (sfx[bs] - hist[bs]);
            s_prefix = prefix | ((unsigned int)bs << shift);
        }
        __syncthreads();
        prefix = s_prefix;
        kk = s_kk;
        __syncthreads();
    }
    const unsigned int vstar = prefix;
    const int need = kk;

    constexpr int PER = D / TPK;  // 16
    const int base = t * PER;
    float vals[PER];
    unsigned int keys[PER];
    int cnt = 0;
    #pragma unroll
    for (int j = 0; j < PER; ++j) {
        const float f = samp[base + j];
        vals[j] = f;
        keys[j] = __float_as_uint(f) & 0x7fffffffu;
        cnt += (keys[j] == vstar) ? 1 : 0;
    }
    int inc = cnt;
    #pragma unroll
    for (int o = 1; o < 64; o <<= 1) {
        const int n = __shfl_up(inc, o, 64);
        if (lane >= o) inc += n;
    }
    if (lane == 63) wsum[wid] = inc;
    __syncthreads();
    int woff = 0;
    for (int w = 0; w < wid; ++w) woff += wsum[w];
    int offset = woff + inc - cnt;
    #pragma unroll
    for (int j = 0; j < PER; ++j) {
        float o2 = 0.0f;
        if (keys[j] > vstar) {
            o2 = vals[j];
        } else if (keys[j] == vstar) {
            if (offset < need) o2 = vals[j];
            offset++;
        }
        out[base + j] = o2;
    }

    if (wid == 0) {
        double s = 0;
        for (int g = lane; g < GLP; g += 64) s += lpp[g];
        s = wredsum(s);
        if (lane == 0) {
            const double c = -log(0.05) - 0.5 * log(2.0 * 3.14159265358979323846);
            out[D] = (float)(-0.5 * s + (double)D * c);
        }
    }
}

extern "C" void kernel_launch(void* const* d_in, const int* in_sizes, int n_in,
                              void* d_out, int out_size, void* d_ws, size_t ws_size,
                              hipStream_t stream) {
    const float* ct    = (const float*)d_in[0];
    const float* W1    = (const float*)d_in[1];
    const float* b1    = (const float*)d_in[2];
    const float* W2    = (const float*)d_in[3];
    const float* b2    = (const float*)d_in[4];
    const float* W3    = (const float*)d_in[5];
    const float* b3    = (const float*)d_in[6];
    const float* qm    = (const float*)d_in[7];
    const float* noise = (const float*)d_in[8];
    const int*   kp    = (const int*)d_in[9];

    // split-K geometry: 512 blocks per matvec (2 blocks/CU at 65KB LDS)
    constexpr int KC1 = 128, KC2 = 32, KC3 = 128;
    constexpr int G1 = D / KC1;   // 128
    constexpr int G2 = H / KC2;   // 128
    constexpr int G3 = H / KC3;   // 32
    constexpr int GLP = D / 256;  // 64

    // ws: p1[128][4096] | p2[128][4096] | p3[32][16384] | x2[H] | x3[H] |
    //     samp[D] f32 | lpp[GLP]
    double* p1   = (double*)d_ws;
    double* p2   = p1 + (size_t)G1 * H;
    double* p3   = p2 + (size_t)G2 * H;
    double* x2   = p3 + (size_t)G3 * D;
    double* x3   = x2 + H;
    float*  samp = (float*)(x3 + H);
    double* lpp  = (double*)(samp + D);

    k_mv<KC1><<<dim3(H / 1024, G1), 256, 0, stream>>>(W1, H, ct, nullptr, p1);
    k_reduce_x<<<dim3(H / 256), 256, 0, stream>>>(p1, G1, H, b1, x2);
    k_mv<KC2><<<dim3(H / 1024, G2), 256, 0, stream>>>(W2, H, nullptr, x2, p2);
    k_reduce_x<<<dim3(H / 256), 256, 0, stream>>>(p2, G2, H, b2, x3);
    k_mv<KC3><<<dim3(D / 1024, G3), 256, 0, stream>>>(W3, D, nullptr, x3, p3);
    k_finalize<<<dim3(D / 256), 256, 0, stream>>>(p3, G3, b3, qm, ct, noise, samp, lpp);
    k_topk<<<dim3(1), TPK, 0, stream>>>(samp, kp, lpp, GLP, (float*)d_out);
}